// Round 12
// baseline (201.398 us; speedup 1.0000x reference)
//
#include <hip/hip_runtime.h>
#include <math.h>

typedef unsigned int   u32;
typedef unsigned long long u64;

#define BATCH   8
#define NDATA   8192
#define NPOINT  1024
#define NSAMPLE 32
#define CFEAT   64
#define ROWF    67          // 3 xyz + 64 feat
#define MAXCAND 128         // P(#in-radius > 128) ~ 0 (lambda <= ~18)
#define QPB     4           // queries per block = waves per block (QPW=1)
#define PF      4           // prefetch chunk (scan steps)
#define NCH     (NDATA/64/PF)   // 32 chunks

// f32-element offsets of the concatenated outputs
#define OUT_IDX (BATCH*NPOINT*NSAMPLE*ROWF)              // 17563648
#define OUT_GX  (OUT_IDX + BATCH*NPOINT*NSAMPLE)         // 17825792

// f32 -> bf16 (RNE) -> f32: match the harness's bf16-rounded np reference
__device__ __forceinline__ float rnbf(float f) {
    u32 b = __float_as_uint(f);
    b += 0x7FFFu + ((b >> 16) & 1u);
    return __uint_as_float(b & 0xFFFF0000u);
}
__device__ __forceinline__ int clampidx(int v) {
    return (v < 0) ? 0 : (v > NDATA-1 ? NDATA-1 : v);
}

__global__ __launch_bounds__(256, 8)   // 8 waves/EU -> 32 waves/CU, VGPR <= 64
void grouping_kernel(const float* __restrict__ new_xyz,
                     const float* __restrict__ xyz,
                     const float* __restrict__ points,
                     float* __restrict__ out, float T)
{
    __shared__ float cand_s[QPB][MAXCAND];   // f32 sqrt(d2), slot order = ascending idx
    __shared__ int   cand_i[QPB][MAXCAND];
    __shared__ int   sel[QPB][NSAMPLE];

    const int tid  = threadIdx.x;
    const int wv   = tid >> 6;
    const int lane = tid & 63;
    const int q    = blockIdx.x * QPB + wv;   // one query per wave, < 8192
    const int b    = q >> 10;                 // batch (4 | 1024)

    if (lane < NSAMPLE) sel[wv][lane] = 0;    // safety net; overwritten below

    const float qx = new_xyz[q*3 + 0];
    const float qy = new_xyz[q*3 + 1];
    const float qz = new_xyz[q*3 + 2];
    const float* bx = xyz + (size_t)b * NDATA * 3;   // 96 KB/batch, L2-resident
    const float* pl = bx + lane*3;                   // this lane's point-0

    // ---- scan: explicit 2-buffer prefetch, immediate-offset loads ----
    int n = 0;                                        // wave-uniform candidate count
    float px[2][PF], py[2][PF], pz[2][PF];
    #pragma unroll
    for (int u = 0; u < PF; ++u) {                    // preload chunk 0
        px[0][u] = pl[u*192 + 0];
        py[0][u] = pl[u*192 + 1];
        pz[0][u] = pl[u*192 + 2];
    }
    const float* pn = pl + PF*192;                    // prefetch cursor (chunk c+1)

    for (int c = 0; c < NCH; ++c) {
        const int cur = c & 1, nxt = cur ^ 1;
        const float* ps = (c + 1 < NCH) ? pn : pl;    // last chunk: harmless re-read
        #pragma unroll
        for (int u = 0; u < PF; ++u) {                // issue next chunk's loads FIRST
            px[nxt][u] = ps[u*192 + 0];
            py[nxt][u] = ps[u*192 + 1];
            pz[nxt][u] = ps[u*192 + 2];
        }
        #pragma unroll
        for (int u = 0; u < PF; ++u) {                // compute on current chunk
            // exact np f32 semantics: no FMA, left-to-right sum
            float dx = __fsub_rn(px[cur][u], qx);
            float dy = __fsub_rn(py[cur][u], qy);
            float dz = __fsub_rn(pz[cur][u], qz);
            float d2 = __fadd_rn(__fadd_rn(__fmul_rn(dx,dx), __fmul_rn(dy,dy)),
                                 __fmul_rn(dz,dz));
            bool cc = d2 < T;                         // == sqrtf(d2) < 0.2f (monotone)
            u64 m = __ballot(cc);
            if (m) {                                  // rare (~12%)
                if (cc) {
                    int below = __builtin_amdgcn_mbcnt_hi((u32)(m >> 32),
                                 __builtin_amdgcn_mbcnt_lo((u32)m, 0));
                    int pos = n + below;
                    if (pos < MAXCAND) {
                        cand_s[wv][pos] = __fsqrt_rn(d2);   // ref sorts the f32 norm
                        cand_i[wv][pos] = ((c*PF + u) << 6) + lane;
                    }
                }
                n += (int)__popcll(m);
            }
        }
        pn += PF*192;
    }

    // ---- rare second pass: argmin for empty-ball queries (wave-uniform) ----
    int mini = 0;
    if (n == 0) {
        float mind = 3.402823466e38f; int mi = 0;
        for (int k = 0; k < NDATA/64; ++k) {
            int i = (k << 6) + lane;
            float dx = __fsub_rn(bx[i*3+0], qx);
            float dy = __fsub_rn(bx[i*3+1], qy);
            float dz = __fsub_rn(bx[i*3+2], qz);
            float d2 = __fadd_rn(__fadd_rn(__fmul_rn(dx,dx), __fmul_rn(dy,dy)),
                                 __fmul_rn(dz,dz));
            if (d2 < mind) { mind = d2; mi = i; }     // strict <: lowest idx per lane
        }
        float ms = __fsqrt_rn(mind);                  // np tie rule is on sqrt values
        for (int off = 32; off; off >>= 1) {
            float os = __shfl_xor(ms, off);
            int   oi = __shfl_xor(mi, off);
            if (os < ms || (os == ms && oi < mi)) { ms = os; mi = oi; }
        }
        mini = mi;
    }

    __syncthreads();   // publish compaction + sel init (uniform path)

    // ---- parallel rank-place: (s, slot) lex == stable argsort by distance ----
    const int nj = n > MAXCAND ? MAXCAND : n;
    for (int kk = lane; kk < nj; kk += 64) {
        float sk = cand_s[wv][kk];
        int r = 0;
        for (int mm = 0; mm < nj; ++mm) {             // broadcast LDS reads
            float sm = cand_s[wv][mm];
            r += (int)((sm < sk) | ((sm == sk) & (mm < kk)));
        }
        if (r < NSAMPLE) sel[wv][r] = clampidx(cand_i[wv][kk]);
    }
    __syncthreads();
    {
        const int nsel = nj < NSAMPLE ? nj : NSAMPLE;
        if (lane >= nsel && lane < NSAMPLE) {
            int pad = (nj > 0) ? sel[wv][0] : clampidx(mini);   // sorted_idx[0]
            sel[wv][lane] = pad;
        }
    }
    __syncthreads();

    // ---- outputs: f32 stores, values pre-rounded through bf16 ----
    // idx (chunk 1)
    if (lane < NSAMPLE)
        out[OUT_IDX + (size_t)q*NSAMPLE + lane] = rnbf((float)sel[wv][lane]);

    // grouped_xyz (chunk 2) + xyz columns of new_points (chunk 0)
    for (int e = lane; e < NSAMPLE*3; e += 64) {
        int sR = e / 3, c2 = e - sR*3;
        int is = sel[wv][sR];
        float v = rnbf(bx[is*3 + c2]);
        out[OUT_GX + (size_t)q*(NSAMPLE*3) + e] = v;
        out[(size_t)q*(NSAMPLE*ROWF) + sR*ROWF + c2] = v;
    }

    // new_points feature columns: 32 rows x 64 feats, 256 B contiguous per row
    const float* prow = points + (size_t)b * NDATA * CFEAT;
    float* onp = out + (size_t)q * (NSAMPLE*ROWF);
    #pragma unroll 8
    for (int r = 0; r < NSAMPLE; ++r) {
        int is = sel[wv][r];
        onp[r*ROWF + 3 + lane] = rnbf(prow[(size_t)is * CFEAT + lane]);
    }
}

extern "C" void kernel_launch(void* const* d_in, const int* in_sizes, int n_in,
                              void* d_out, int out_size, void* d_ws, size_t ws_size,
                              hipStream_t stream) {
    // T = smallest f32 x with sqrtf(x) >= 0.2f  =>  (d2 < T) == (sqrtf(d2) < 0.2f)
    union { u32 u; float f; } lo, hi, mid;
    lo.u = 0u; hi.f = 0.05f;
    while (hi.u - lo.u > 1u) {
        mid.u = lo.u + (hi.u - lo.u) / 2u;
        if (sqrtf(mid.f) >= 0.2f) hi.u = mid.u; else lo.u = mid.u;
    }
    float T = hi.f;

    grouping_kernel<<<(BATCH*NPOINT)/QPB, 256, 0, stream>>>(
        (const float*)d_in[0],   // new_xyz (f32)
        (const float*)d_in[1],   // xyz     (f32)
        (const float*)d_in[2],   // points  (f32)
        (float*)d_out, T);
}

// Round 13
// 132.540 us; speedup vs baseline: 1.5195x; 1.5195x over previous
//
#include <hip/hip_runtime.h>
#include <math.h>

typedef unsigned int   u32;
typedef unsigned long long u64;

#define BATCH   8
#define NDATA   8192
#define NPOINT  1024
#define NSAMPLE 32
#define CFEAT   64
#define ROWF    67          // 3 xyz + 64 feat
#define MAXCAND 128         // P(#in-radius > 128) ~ 0
#define QPB     4           // queries per block = waves per block
#define TILE    512         // points per LDS tile
#define DWT     (TILE*3)    // 1536 dwords per tile
#define NT      (NDATA/TILE) // 16 tiles

// f32-element offsets of the concatenated outputs
#define OUT_IDX (BATCH*NPOINT*NSAMPLE*ROWF)              // 17563648
#define OUT_GX  (OUT_IDX + BATCH*NPOINT*NSAMPLE)         // 17825792

// f32 -> bf16 (RNE) -> f32: match the harness's bf16-rounded np reference
__device__ __forceinline__ float rnbf(float f) {
    u32 b = __float_as_uint(f);
    b += 0x7FFFu + ((b >> 16) & 1u);
    return __uint_as_float(b & 0xFFFF0000u);
}
__device__ __forceinline__ int clampidx(int v) {
    return (v < 0) ? 0 : (v > NDATA-1 ? NDATA-1 : v);
}

__global__ __launch_bounds__(256, 8)   // 8 blocks/CU -> 32 waves/CU, VGPR <= 64
void grouping_kernel(const float* __restrict__ new_xyz,
                     const float* __restrict__ xyz,
                     const float* __restrict__ points,
                     float* __restrict__ out, float T)
{
    __shared__ u32   tileb[2][DWT];          // raw AoS xyz dwords (2 x 6 KB)
    __shared__ float cand_s[QPB][MAXCAND];   // f32 sqrt(d2), slot order = ascending idx
    __shared__ int   cand_i[QPB][MAXCAND];
    __shared__ int   sel[QPB][NSAMPLE];

    const int tid  = threadIdx.x;
    const int wv   = tid >> 6;
    const int lane = tid & 63;
    const int q    = blockIdx.x * QPB + wv;   // one query per wave, < 8192
    const int b    = q >> 10;                 // batch (uniform per block: 4 | 1024)

    if (lane < NSAMPLE) sel[wv][lane] = 0;    // safety net; overwritten below

    const float qx = new_xyz[q*3 + 0];
    const float qy = new_xyz[q*3 + 1];
    const float qz = new_xyz[q*3 + 2];
    const float* bx = xyz + (size_t)b * NDATA * 3;   // 96 KB/batch, L2-resident
    const u32*   src = (const u32*)bx;

    // ---- stage tile 0 (fully coalesced: lane i -> dword i) ----
    #pragma unroll
    for (int k = 0; k < DWT/256; ++k)
        tileb[0][k*256 + tid] = src[k*256 + tid];
    __syncthreads();

    // ---- scan: LDS tiles, conflict-free stride-3 reads ----
    int n = 0;                                 // wave-uniform candidate count
    for (int t = 0; t < NT; ++t) {
        const int cur = t & 1, nxt = cur ^ 1;
        if (t + 1 < NT) {                      // stage next tile (coalesced)
            #pragma unroll
            for (int k = 0; k < DWT/256; ++k)
                tileb[nxt][k*256 + tid] = src[(t+1)*DWT + k*256 + tid];
        }
        #pragma unroll 2
        for (int u = 0; u < TILE/64; ++u) {
            int il = (u << 6) + lane;          // tile-local point index
            const u32* tb = &tileb[cur][il*3];
            float x = __uint_as_float(tb[0]);
            float y = __uint_as_float(tb[1]);
            float z = __uint_as_float(tb[2]);
            // exact np f32 semantics: no FMA, left-to-right sum
            float dx = __fsub_rn(x, qx), dy = __fsub_rn(y, qy), dz = __fsub_rn(z, qz);
            float d2 = __fadd_rn(__fadd_rn(__fmul_rn(dx,dx), __fmul_rn(dy,dy)),
                                 __fmul_rn(dz,dz));
            bool cc = d2 < T;                  // == sqrtf(d2) < 0.2f (monotone)
            u64 m = __ballot(cc);
            if (m) {                           // rare (~12% of steps)
                if (cc) {
                    int below = __builtin_amdgcn_mbcnt_hi((u32)(m >> 32),
                                 __builtin_amdgcn_mbcnt_lo((u32)m, 0));
                    int pos = n + below;
                    if (pos < MAXCAND) {
                        cand_s[wv][pos] = __fsqrt_rn(d2);   // ref sorts the f32 norm
                        cand_i[wv][pos] = t*TILE + il;
                    }
                }
                n += (int)__popcll(m);
            }
        }
        __syncthreads();   // block-uniform: compute done + next tile staged
    }

    // ---- rare second pass: argmin for empty-ball queries (~6% of waves) ----
    int mini = 0;
    if (n == 0) {
        float mind = 3.402823466e38f; int mi = 0;
        for (int k = 0; k < NDATA/64; ++k) {
            int i = (k << 6) + lane;
            float dx = __fsub_rn(bx[i*3+0], qx);
            float dy = __fsub_rn(bx[i*3+1], qy);
            float dz = __fsub_rn(bx[i*3+2], qz);
            float d2 = __fadd_rn(__fadd_rn(__fmul_rn(dx,dx), __fmul_rn(dy,dy)),
                                 __fmul_rn(dz,dz));
            if (d2 < mind) { mind = d2; mi = i; }   // strict <: lowest idx per lane
        }
        float ms = __fsqrt_rn(mind);                 // np tie rule on sqrt values
        for (int off = 32; off; off >>= 1) {
            float os = __shfl_xor(ms, off);
            int   oi = __shfl_xor(mi, off);
            if (os < ms || (os == ms && oi < mi)) { ms = os; mi = oi; }
        }
        mini = mi;
    }

    __syncthreads();

    // ---- parallel rank-place: (s, slot) lex == stable argsort by distance ----
    const int nj = n > MAXCAND ? MAXCAND : n;
    for (int kk = lane; kk < nj; kk += 64) {
        float sk = cand_s[wv][kk];
        int r = 0;
        for (int mm = 0; mm < nj; ++mm) {            // broadcast LDS reads
            float sm = cand_s[wv][mm];
            r += (int)((sm < sk) | ((sm == sk) & (mm < kk)));
        }
        if (r < NSAMPLE) sel[wv][r] = clampidx(cand_i[wv][kk]);
    }
    __syncthreads();
    {
        const int nsel = nj < NSAMPLE ? nj : NSAMPLE;
        if (lane >= nsel && lane < NSAMPLE) {
            int pad = (nj > 0) ? sel[wv][0] : clampidx(mini);   // sorted_idx[0]
            sel[wv][lane] = pad;
        }
    }
    __syncthreads();

    // ---- outputs: f32 stores, values pre-rounded through bf16 ----
    // idx (chunk 1): 128 B/query, line-aligned
    if (lane < NSAMPLE)
        out[OUT_IDX + (size_t)q*NSAMPLE + lane] = rnbf((float)sel[wv][lane]);

    // grouped_xyz (chunk 2): 384 B/query
    for (int e = lane; e < NSAMPLE*3; e += 64) {
        int sR = e / 3, c2 = e - sR*3;
        int is = sel[wv][sR];
        out[OUT_GX + (size_t)q*(NSAMPLE*3) + e] = rnbf(bx[is*3 + c2]);
    }

    // new_points (chunk 0): unified row-major pass -> each 64 B line written once
    const float* prow = points + (size_t)b * NDATA * CFEAT;
    float* onp = out + (size_t)q * (NSAMPLE*ROWF);
    for (int e = lane; e < NSAMPLE*ROWF; e += 64) {
        int s  = e / ROWF;                // compiler magic-mul
        int c  = e - s*ROWF;
        int is = sel[wv][s];
        const float* ap = (c < 3) ? (bx + (size_t)is*3 + c)
                                  : (prow + (size_t)is*CFEAT + (c-3));
        onp[e] = rnbf(*ap);
    }
}

extern "C" void kernel_launch(void* const* d_in, const int* in_sizes, int n_in,
                              void* d_out, int out_size, void* d_ws, size_t ws_size,
                              hipStream_t stream) {
    // T = smallest f32 x with sqrtf(x) >= 0.2f  =>  (d2 < T) == (sqrtf(d2) < 0.2f)
    union { u32 u; float f; } lo, hi, mid;
    lo.u = 0u; hi.f = 0.05f;
    while (hi.u - lo.u > 1u) {
        mid.u = lo.u + (hi.u - lo.u) / 2u;
        if (sqrtf(mid.f) >= 0.2f) hi.u = mid.u; else lo.u = mid.u;
    }
    float T = hi.f;

    grouping_kernel<<<(BATCH*NPOINT)/QPB, 256, 0, stream>>>(
        (const float*)d_in[0],   // new_xyz (f32)
        (const float*)d_in[1],   // xyz     (f32)
        (const float*)d_in[2],   // points  (f32)
        (float*)d_out, T);
}